// Round 1
// baseline (1181.197 us; speedup 1.0000x reference)
//
#include <hip/hip_runtime.h>
#include <math.h>

#define B_ 32
#define N_ 1024
#define E_ 2048
#define DD 11   // d = D + Hd = 3 + 8
#define HD 8

// ---------------- input network: H = [tanh(X@Wi+bi), X] ----------------
__global__ void k_input(const float* __restrict__ X, const float* __restrict__ Wi,
                        const float* __restrict__ bi, float* __restrict__ H) {
    int idx = blockIdx.x * 256 + threadIdx.x;
    if (idx >= B_ * N_) return;
    float x0 = X[idx * 3 + 0], x1 = X[idx * 3 + 1], x2 = X[idx * 3 + 2];
    float* h = H + (size_t)idx * DD;
    #pragma unroll
    for (int j = 0; j < HD; j++)
        h[j] = tanhf(x0 * Wi[0 * HD + j] + x1 * Wi[1 * HD + j] + x2 * Wi[2 * HD + j] + bi[j]);
    h[8] = x0; h[9] = x1; h[10] = x2;
}

// ---------------- gather: bo[b,e,:] = sum_n Ro[b,n,e] H[b,n,:], bi likewise (Ri) ----
// partial layout: part[m][s][b][d][e], m=0 -> bo (Ro), m=1 -> bi (Ri)
__global__ __launch_bounds__(256) void k_gather(const float* __restrict__ Ri,
        const float* __restrict__ Ro, const float* __restrict__ H,
        float* __restrict__ part, int NS) {
    int bid = blockIdx.x;
    int eb = (bid & 7) * 256;            // E_/256 = 8 edge tiles
    int s  = (bid >> 3) % NS;
    int b  = bid / (8 * NS);
    int e  = eb + threadIdx.x;
    int nper = N_ / NS;
    int n0 = s * nper;

    float ao[DD], ai[DD];
    #pragma unroll
    for (int d = 0; d < DD; d++) { ao[d] = 0.f; ai[d] = 0.f; }

    const float* ri = Ri + ((size_t)b * N_ + n0) * E_ + e;
    const float* ro = Ro + ((size_t)b * N_ + n0) * E_ + e;
    const float* hp = H + ((size_t)b * N_ + n0) * DD;   // uniform across wave -> scalar loads

    #pragma unroll 4
    for (int n = 0; n < nper; n++) {
        float vo = ro[(size_t)n * E_];
        float vi = ri[(size_t)n * E_];
        #pragma unroll
        for (int d = 0; d < DD; d++) {
            float hv = hp[n * DD + d];
            ao[d] = fmaf(vo, hv, ao[d]);
            ai[d] = fmaf(vi, hv, ai[d]);
        }
    }
    size_t base_o = ((size_t)(s * B_ + b)) * DD * E_ + e;
    size_t base_i = ((size_t)((NS + s) * B_ + b)) * DD * E_ + e;
    #pragma unroll
    for (int d = 0; d < DD; d++) {
        part[base_o + (size_t)d * E_] = ao[d];
        part[base_i + (size_t)d * E_] = ai[d];
    }
}

// ---------------- edge finish: reduce partials, edge MLP, weight bo/bi by ew ------
__global__ void k_edge_finish(const float* __restrict__ part,
        const float* __restrict__ We1, const float* __restrict__ be1,
        const float* __restrict__ We2, const float* __restrict__ be2,
        float* __restrict__ wbo, float* __restrict__ wbi,
        float* __restrict__ out, int NS, int final_) {
    int idx = blockIdx.x * 256 + threadIdx.x;   // over B*E
    if (idx >= B_ * E_) return;
    int b = idx / E_, e = idx % E_;

    float bo[DD], bi_[DD];
    #pragma unroll
    for (int d = 0; d < DD; d++) { bo[d] = 0.f; bi_[d] = 0.f; }
    for (int s = 0; s < NS; s++) {
        size_t po = ((size_t)(s * B_ + b)) * DD * E_ + e;
        size_t pi = ((size_t)((NS + s) * B_ + b)) * DD * E_ + e;
        #pragma unroll
        for (int d = 0; d < DD; d++) {
            bo[d]  += part[po + (size_t)d * E_];
            bi_[d] += part[pi + (size_t)d * E_];
        }
    }
    float h[HD];
    #pragma unroll
    for (int j = 0; j < HD; j++) {
        float acc = be1[j];
        #pragma unroll
        for (int d = 0; d < DD; d++) acc = fmaf(bo[d],  We1[d * HD + j], acc);
        #pragma unroll
        for (int d = 0; d < DD; d++) acc = fmaf(bi_[d], We1[(DD + d) * HD + j], acc);
        h[j] = tanhf(acc);
    }
    float sacc = be2[0];
    #pragma unroll
    for (int j = 0; j < HD; j++) sacc = fmaf(h[j], We2[j], sacc);
    float ew = 1.f / (1.f + expf(-sacc));

    if (final_) {
        out[idx] = ew;
    } else {
        #pragma unroll
        for (int d = 0; d < DD; d++) {
            wbo[(size_t)idx * DD + d] = ew * bo[d];
            wbi[(size_t)idx * DD + d] = ew * bi_[d];
        }
    }
}

// ---------------- scatter: mi[b,n,:] = sum_e Ri[b,n,e] wbo[b,e,:]; mo (Ro,wbi) ----
// partial layout: part[m][s][b][d][n], m=0 -> mi, m=1 -> mo
__global__ __launch_bounds__(256) void k_scatter(const float* __restrict__ Ri,
        const float* __restrict__ Ro, const float* __restrict__ wbo,
        const float* __restrict__ wbi, float* __restrict__ part, int NS) {
    __shared__ float T[256][33];   // 33.8 KB, pad -> conflict-free column reads
    int bid = blockIdx.x;
    int nt = bid & 3;                // N_/256 = 4 node tiles
    int s  = (bid >> 2) % NS;
    int b  = bid / (4 * NS);
    int n0 = nt * 256;
    int eper = E_ / NS;
    int e0 = s * eper;
    int tid = threadIdx.x;
    int col = tid & 31, r0 = tid >> 5;

    float mi[DD], mo[DD];
    #pragma unroll
    for (int d = 0; d < DD; d++) { mi[d] = 0.f; mo[d] = 0.f; }

    for (int ec = e0; ec < e0 + eper; ec += 32) {
        // phase A: Ri tile -> mi (uses weighted bo)
        #pragma unroll 8
        for (int k = 0; k < 32; k++) {
            int row = r0 + k * 8;
            T[row][col] = Ri[((size_t)b * N_ + n0 + row) * E_ + ec + col];
        }
        __syncthreads();
        #pragma unroll 4
        for (int j = 0; j < 32; j++) {
            float vi = T[tid][j];
            const float* po = wbo + ((size_t)b * E_ + ec + j) * DD;  // uniform -> scalar loads
            #pragma unroll
            for (int d = 0; d < DD; d++) mi[d] = fmaf(vi, po[d], mi[d]);
        }
        __syncthreads();
        // phase B: Ro tile -> mo (uses weighted bi)
        #pragma unroll 8
        for (int k = 0; k < 32; k++) {
            int row = r0 + k * 8;
            T[row][col] = Ro[((size_t)b * N_ + n0 + row) * E_ + ec + col];
        }
        __syncthreads();
        #pragma unroll 4
        for (int j = 0; j < 32; j++) {
            float vo = T[tid][j];
            const float* pi = wbi + ((size_t)b * E_ + ec + j) * DD;
            #pragma unroll
            for (int d = 0; d < DD; d++) mo[d] = fmaf(vo, pi[d], mo[d]);
        }
        __syncthreads();
    }
    size_t bmi = ((size_t)(s * B_ + b)) * DD * N_ + n0 + tid;
    size_t bmo = ((size_t)((NS + s) * B_ + b)) * DD * N_ + n0 + tid;
    #pragma unroll
    for (int d = 0; d < DD; d++) {
        part[bmi + (size_t)d * N_] = mi[d];
        part[bmo + (size_t)d * N_] = mo[d];
    }
}

// ---------------- node finish: reduce partials, node MLP, H = [tanh(.), X] -------
__global__ void k_node_finish(const float* __restrict__ part,
        const float* __restrict__ Wn1, const float* __restrict__ bn1,
        const float* __restrict__ Wn2, const float* __restrict__ bn2,
        float* __restrict__ H, int NS) {
    int idx = blockIdx.x * 256 + threadIdx.x;   // over B*N
    if (idx >= B_ * N_) return;
    int b = idx / N_, n = idx % N_;

    float mi[DD], mo[DD];
    #pragma unroll
    for (int d = 0; d < DD; d++) { mi[d] = 0.f; mo[d] = 0.f; }
    for (int s = 0; s < NS; s++) {
        size_t pmi = ((size_t)(s * B_ + b)) * DD * N_ + n;
        size_t pmo = ((size_t)((NS + s) * B_ + b)) * DD * N_ + n;
        #pragma unroll
        for (int d = 0; d < DD; d++) {
            mi[d] += part[pmi + (size_t)d * N_];
            mo[d] += part[pmo + (size_t)d * N_];
        }
    }
    float* h = H + (size_t)idx * DD;
    float hold[DD];
    #pragma unroll
    for (int d = 0; d < DD; d++) hold[d] = h[d];

    float t1[HD];
    #pragma unroll
    for (int j = 0; j < HD; j++) {
        float acc = bn1[j];
        #pragma unroll
        for (int d = 0; d < DD; d++) acc = fmaf(mi[d],   Wn1[d * HD + j], acc);
        #pragma unroll
        for (int d = 0; d < DD; d++) acc = fmaf(mo[d],   Wn1[(DD + d) * HD + j], acc);
        #pragma unroll
        for (int d = 0; d < DD; d++) acc = fmaf(hold[d], Wn1[(2 * DD + d) * HD + j], acc);
        t1[j] = tanhf(acc);
    }
    #pragma unroll
    for (int j = 0; j < HD; j++) {
        float acc = bn2[j];
        #pragma unroll
        for (int k = 0; k < HD; k++) acc = fmaf(t1[k], Wn2[k * HD + j], acc);
        h[j] = tanhf(acc);   // h[8..10] keep X
    }
}

extern "C" void kernel_launch(void* const* d_in, const int* in_sizes, int n_in,
                              void* d_out, int out_size, void* d_ws, size_t ws_size,
                              hipStream_t stream) {
    const float* X   = (const float*)d_in[0];
    const float* Ri  = (const float*)d_in[1];
    const float* Ro  = (const float*)d_in[2];
    const float* Wi  = (const float*)d_in[3];
    const float* bi  = (const float*)d_in[4];
    const float* We1 = (const float*)d_in[5];
    const float* be1 = (const float*)d_in[6];
    const float* We2 = (const float*)d_in[7];
    const float* be2 = (const float*)d_in[8];
    const float* Wn1 = (const float*)d_in[9];
    const float* bn1 = (const float*)d_in[10];
    const float* Wn2 = (const float*)d_in[11];
    const float* bn2 = (const float*)d_in[12];
    float* out = (float*)d_out;

    size_t fl = ws_size / sizeof(float);
    int NSG = 2, NSS = 4;
    auto need = [](int g, int s) -> size_t {
        return (size_t)B_ * N_ * DD            // H
             + 2ull * g * B_ * DD * E_         // gather partials
             + 2ull * B_ * E_ * DD             // wbo, wbi
             + 2ull * s * B_ * DD * N_;        // scatter partials
    };
    if (need(NSG, NSS) > fl) { NSG = 1; NSS = 2; }
    if (need(NSG, NSS) > fl) { NSG = 1; NSS = 1; }

    float* ws    = (float*)d_ws;
    float* H     = ws;  ws += (size_t)B_ * N_ * DD;
    float* gpart = ws;  ws += 2ull * NSG * B_ * DD * E_;
    float* wbo   = ws;  ws += (size_t)B_ * E_ * DD;
    float* wbi   = ws;  ws += (size_t)B_ * E_ * DD;
    float* spart = ws;

    k_input<<<(B_ * N_ + 255) / 256, 256, 0, stream>>>(X, Wi, bi, H);
    for (int it = 0; it < 3; it++) {
        k_gather<<<B_ * 8 * NSG, 256, 0, stream>>>(Ri, Ro, H, gpart, NSG);
        k_edge_finish<<<(B_ * E_ + 255) / 256, 256, 0, stream>>>(
            gpart, We1, be1, We2, be2, wbo, wbi, out, NSG, 0);
        k_scatter<<<B_ * 4 * NSS, 256, 0, stream>>>(Ri, Ro, wbo, wbi, spart, NSS);
        k_node_finish<<<(B_ * N_ + 255) / 256, 256, 0, stream>>>(
            spart, Wn1, bn1, Wn2, bn2, H, NSS);
    }
    k_gather<<<B_ * 8 * NSG, 256, 0, stream>>>(Ri, Ro, H, gpart, NSG);
    k_edge_finish<<<(B_ * E_ + 255) / 256, 256, 0, stream>>>(
        gpart, We1, be1, We2, be2, wbo, wbi, out, NSG, 1);
}

// Round 2
// 912.444 us; speedup vs baseline: 1.2945x; 1.2945x over previous
//
#include <hip/hip_runtime.h>
#include <math.h>

#define B_ 32
#define N_ 1024
#define E_ 2048
#define DD 11   // d = D + Hd = 3 + 8
#define HD 8

// ---------------- input network: H = [tanh(X@Wi+bi), X] ----------------
__global__ void k_input(const float* __restrict__ X, const float* __restrict__ Wi,
                        const float* __restrict__ bi, float* __restrict__ H) {
    int idx = blockIdx.x * 256 + threadIdx.x;
    if (idx >= B_ * N_) return;
    float x0 = X[idx * 3 + 0], x1 = X[idx * 3 + 1], x2 = X[idx * 3 + 2];
    float* h = H + (size_t)idx * DD;
    #pragma unroll
    for (int j = 0; j < HD; j++)
        h[j] = tanhf(x0 * Wi[0 * HD + j] + x1 * Wi[1 * HD + j] + x2 * Wi[2 * HD + j] + bi[j]);
    h[8] = x0; h[9] = x1; h[10] = x2;
}

// ---------------- fused gather + edge MLP ----------------
// grid = B * (E/64); block = 256 (4 waves). Wave w sums n in [w*256,(w+1)*256),
// lanes cover 64 consecutive e. LDS reduce across waves, wave 0 runs edge MLP.
__global__ __launch_bounds__(256) void k_edge(
        const float* __restrict__ Ri, const float* __restrict__ Ro,
        const float* __restrict__ H,
        const float* __restrict__ We1, const float* __restrict__ be1,
        const float* __restrict__ We2, const float* __restrict__ be2,
        float* __restrict__ wbo, float* __restrict__ wbi,
        float* __restrict__ out, int final_) {
    __shared__ float red[3][64][2 * DD];   // 16.9 KB
    int bid = blockIdx.x;
    int eb = (bid & 31) << 6;          // E/64 = 32 edge tiles
    int b  = bid >> 5;
    int tid = threadIdx.x;
    int w = tid >> 6, lane = tid & 63;
    int e = eb + lane;
    int n0 = w << 8;                   // 256 n per wave

    float ao[DD], ai[DD];
    #pragma unroll
    for (int d = 0; d < DD; d++) { ao[d] = 0.f; ai[d] = 0.f; }

    const float* ri = Ri + ((size_t)b * N_ + n0) * E_ + e;
    const float* ro = Ro + ((size_t)b * N_ + n0) * E_ + e;
    int hbase = __builtin_amdgcn_readfirstlane((b * N_ + n0) * DD);
    const float* hp = H + hbase;       // wave-uniform -> scalar loads

    #pragma unroll 4
    for (int n = 0; n < 256; n++) {
        float vi = ri[(size_t)n * E_];
        float vo = ro[(size_t)n * E_];
        #pragma unroll
        for (int d = 0; d < DD; d++) {
            float hv = hp[n * DD + d];
            ao[d] = fmaf(vo, hv, ao[d]);
            ai[d] = fmaf(vi, hv, ai[d]);
        }
    }
    if (w) {
        #pragma unroll
        for (int d = 0; d < DD; d++) {
            red[w - 1][lane][d]      = ao[d];
            red[w - 1][lane][DD + d] = ai[d];
        }
    }
    __syncthreads();
    if (w == 0) {
        #pragma unroll
        for (int ww = 0; ww < 3; ww++)
            #pragma unroll
            for (int d = 0; d < DD; d++) {
                ao[d] += red[ww][lane][d];
                ai[d] += red[ww][lane][DD + d];
            }
        float h[HD];
        #pragma unroll
        for (int j = 0; j < HD; j++) {
            float acc = be1[j];
            #pragma unroll
            for (int d = 0; d < DD; d++) acc = fmaf(ao[d], We1[d * HD + j], acc);
            #pragma unroll
            for (int d = 0; d < DD; d++) acc = fmaf(ai[d], We1[(DD + d) * HD + j], acc);
            h[j] = tanhf(acc);
        }
        float sacc = be2[0];
        #pragma unroll
        for (int j = 0; j < HD; j++) sacc = fmaf(h[j], We2[j], sacc);
        float ew = 1.f / (1.f + expf(-sacc));

        size_t idx = (size_t)b * E_ + e;
        if (final_) {
            out[idx] = ew;
        } else {
            #pragma unroll
            for (int d = 0; d < DD; d++) {
                wbo[idx * DD + d] = ew * ao[d];
                wbi[idx * DD + d] = ew * ai[d];
            }
        }
    }
}

// ---------------- scatter: mi[b,n,:] = sum_e Ri[b,n,e] wbo[b,e,:]; mo (Ro,wbi) ----
// grid = B * 4(n-tiles) * NS(e-slices); block 256; two LDS tiles [256][18],
// float4 staging with register double-buffer. partial: part[m][s][b][d][n]
__global__ __launch_bounds__(256) void k_scatter(const float* __restrict__ Ri,
        const float* __restrict__ Ro, const float* __restrict__ wbo,
        const float* __restrict__ wbi, float* __restrict__ part, int NS) {
    __shared__ float TA[256][18];   // 18.4 KB, 2-way (free) bank alias
    __shared__ float TB[256][18];
    int bid = blockIdx.x;
    int nt = bid & 3;                  // N/256 = 4 node tiles
    int s  = (bid >> 2) % NS;
    int b  = bid / (4 * NS);
    int n0 = nt << 8;
    int eper = E_ / NS;
    int e0 = s * eper;
    int tid = threadIdx.x;
    int c4 = (tid & 3) << 2;           // float4 column within 16-col chunk
    int r  = tid >> 2;                 // 0..63, rows r, r+64, r+128, r+192

    const float* bRi = Ri + ((size_t)b * N_ + n0) * E_ + e0 + c4;
    const float* bRo = Ro + ((size_t)b * N_ + n0) * E_ + e0 + c4;

    float mi[DD], mo[DD];
    #pragma unroll
    for (int d = 0; d < DD; d++) { mi[d] = 0.f; mo[d] = 0.f; }

    float4 pa[4], pb[4];
    auto LOADC = [&](int ec) {
        #pragma unroll
        for (int k = 0; k < 4; k++) {
            size_t off = (size_t)(r + (k << 6)) * E_ + ec;
            pa[k] = *(const float4*)(bRi + off);
            pb[k] = *(const float4*)(bRo + off);
        }
    };
    auto WRITEC = [&]() {
        #pragma unroll
        for (int k = 0; k < 4; k++) {
            int row = r + (k << 6);
            TA[row][c4 + 0] = pa[k].x; TA[row][c4 + 1] = pa[k].y;
            TA[row][c4 + 2] = pa[k].z; TA[row][c4 + 3] = pa[k].w;
            TB[row][c4 + 0] = pb[k].x; TB[row][c4 + 1] = pb[k].y;
            TB[row][c4 + 2] = pb[k].z; TB[row][c4 + 3] = pb[k].w;
        }
    };

    LOADC(0);
    WRITEC();
    __syncthreads();
    for (int ec = 0; ec < eper; ec += 16) {
        bool more = (ec + 16) < eper;
        if (more) LOADC(ec + 16);
        const float* wo = wbo + ((size_t)b * E_ + e0 + ec) * DD;  // block-uniform -> s_load
        const float* wi = wbi + ((size_t)b * E_ + e0 + ec) * DD;
        #pragma unroll
        for (int j = 0; j < 16; j++) {
            float vA = TA[tid][j];
            float vB = TB[tid][j];
            #pragma unroll
            for (int d = 0; d < DD; d++) {
                mi[d] = fmaf(vA, wo[j * DD + d], mi[d]);
                mo[d] = fmaf(vB, wi[j * DD + d], mo[d]);
            }
        }
        if (more) {
            __syncthreads();
            WRITEC();
            __syncthreads();
        }
    }
    size_t bmi = ((size_t)(s * B_ + b)) * DD * N_ + n0 + tid;
    size_t bmo = ((size_t)((NS + s) * B_ + b)) * DD * N_ + n0 + tid;
    #pragma unroll
    for (int d = 0; d < DD; d++) {
        part[bmi + (size_t)d * N_] = mi[d];
        part[bmo + (size_t)d * N_] = mo[d];
    }
}

// ---------------- node finish: reduce partials, node MLP, H = [tanh(.), X] -------
__global__ void k_node_finish(const float* __restrict__ part,
        const float* __restrict__ Wn1, const float* __restrict__ bn1,
        const float* __restrict__ Wn2, const float* __restrict__ bn2,
        float* __restrict__ H, int NS) {
    int idx = blockIdx.x * 256 + threadIdx.x;   // over B*N
    if (idx >= B_ * N_) return;
    int b = idx / N_, n = idx % N_;

    float mi[DD], mo[DD];
    #pragma unroll
    for (int d = 0; d < DD; d++) { mi[d] = 0.f; mo[d] = 0.f; }
    for (int s = 0; s < NS; s++) {
        size_t pmi = ((size_t)(s * B_ + b)) * DD * N_ + n;
        size_t pmo = ((size_t)((NS + s) * B_ + b)) * DD * N_ + n;
        #pragma unroll
        for (int d = 0; d < DD; d++) {
            mi[d] += part[pmi + (size_t)d * N_];
            mo[d] += part[pmo + (size_t)d * N_];
        }
    }
    float* h = H + (size_t)idx * DD;
    float hold[DD];
    #pragma unroll
    for (int d = 0; d < DD; d++) hold[d] = h[d];

    float t1[HD];
    #pragma unroll
    for (int j = 0; j < HD; j++) {
        float acc = bn1[j];
        #pragma unroll
        for (int d = 0; d < DD; d++) acc = fmaf(mi[d],   Wn1[d * HD + j], acc);
        #pragma unroll
        for (int d = 0; d < DD; d++) acc = fmaf(mo[d],   Wn1[(DD + d) * HD + j], acc);
        #pragma unroll
        for (int d = 0; d < DD; d++) acc = fmaf(hold[d], Wn1[(2 * DD + d) * HD + j], acc);
        t1[j] = tanhf(acc);
    }
    #pragma unroll
    for (int j = 0; j < HD; j++) {
        float acc = bn2[j];
        #pragma unroll
        for (int k = 0; k < HD; k++) acc = fmaf(t1[k], Wn2[k * HD + j], acc);
        h[j] = tanhf(acc);   // h[8..10] keep X
    }
}

extern "C" void kernel_launch(void* const* d_in, const int* in_sizes, int n_in,
                              void* d_out, int out_size, void* d_ws, size_t ws_size,
                              hipStream_t stream) {
    const float* X   = (const float*)d_in[0];
    const float* Ri  = (const float*)d_in[1];
    const float* Ro  = (const float*)d_in[2];
    const float* Wi  = (const float*)d_in[3];
    const float* bi  = (const float*)d_in[4];
    const float* We1 = (const float*)d_in[5];
    const float* be1 = (const float*)d_in[6];
    const float* We2 = (const float*)d_in[7];
    const float* be2 = (const float*)d_in[8];
    const float* Wn1 = (const float*)d_in[9];
    const float* bn1 = (const float*)d_in[10];
    const float* Wn2 = (const float*)d_in[11];
    const float* bn2 = (const float*)d_in[12];
    float* out = (float*)d_out;

    size_t fl = ws_size / sizeof(float);
    int NSS = 8;
    auto need = [](int s) -> size_t {
        return (size_t)B_ * N_ * DD            // H
             + 2ull * B_ * E_ * DD             // wbo, wbi
             + 2ull * s * B_ * DD * N_;        // scatter partials
    };
    if (need(NSS) > fl) NSS = 4;
    if (need(NSS) > fl) NSS = 2;

    float* ws    = (float*)d_ws;
    float* H     = ws;  ws += (size_t)B_ * N_ * DD;
    float* wbo   = ws;  ws += (size_t)B_ * E_ * DD;
    float* wbi   = ws;  ws += (size_t)B_ * E_ * DD;
    float* spart = ws;

    k_input<<<(B_ * N_ + 255) / 256, 256, 0, stream>>>(X, Wi, bi, H);
    for (int it = 0; it < 3; it++) {
        k_edge<<<B_ * 32, 256, 0, stream>>>(Ri, Ro, H, We1, be1, We2, be2,
                                            wbo, wbi, out, 0);
        k_scatter<<<B_ * 4 * NSS, 256, 0, stream>>>(Ri, Ro, wbo, wbi, spart, NSS);
        k_node_finish<<<(B_ * N_ + 255) / 256, 256, 0, stream>>>(
            spart, Wn1, bn1, Wn2, bn2, H, NSS);
    }
    k_edge<<<B_ * 32, 256, 0, stream>>>(Ri, Ro, H, We1, be1, We2, be2,
                                        wbo, wbi, out, 1);
}